// Round 10
// baseline (2237.057 us; speedup 1.0000x reference)
//
#include <hip/hip_runtime.h>

#define FDIM 256
#define GRAM_KS 192

// ---------------- CSR build ----------------
__global__ void k_hist(const int* __restrict__ dst, int* __restrict__ deg, int E) {
  int e = blockIdx.x * 256 + threadIdx.x;
  if (e < E) atomicAdd(&deg[dst[e]], 1);
}

__global__ __launch_bounds__(256) void k_blksum(const int* __restrict__ deg,
    int* __restrict__ blksum, int n) {
  int b = blockIdx.x, tid = threadIdx.x;
  int base = b * 1024 + tid * 4;
  int s = 0;
#pragma unroll
  for (int k = 0; k < 4; ++k) if (base + k < n) s += deg[base + k];
  for (int off = 32; off; off >>= 1) s += __shfl_down(s, off);
  __shared__ int ws4[4];
  if ((tid & 63) == 0) ws4[tid >> 6] = s;
  __syncthreads();
  if (tid == 0) blksum[b] = ws4[0] + ws4[1] + ws4[2] + ws4[3];
}

__global__ void k_blkscan(const int* __restrict__ blksum, int* __restrict__ blkoff, int nblk) {
  int lane = threadIdx.x;
  int carry = 0;
  for (int base = 0; base < nblk; base += 64) {
    int v = (base + lane < nblk) ? blksum[base + lane] : 0;
    int x = v;
    for (int off = 1; off < 64; off <<= 1) { int y = __shfl_up(x, off); if (lane >= off) x += y; }
    if (base + lane < nblk) blkoff[base + lane] = carry + x - v;
    carry += __shfl(x, 63);
  }
}

__global__ __launch_bounds__(256) void k_scan_blk(const int* __restrict__ deg,
    const int* __restrict__ blkoff, int* __restrict__ rowptr, int* __restrict__ cursor, int n) {
  int b = blockIdx.x, tid = threadIdx.x;
  int base = b * 1024 + tid * 4;
  int v[4];
#pragma unroll
  for (int k = 0; k < 4; ++k) v[k] = (base + k < n) ? deg[base + k] : 0;
  int s = v[0] + v[1] + v[2] + v[3];
  int lane = tid & 63, w = tid >> 6;
  int x = s;
  for (int off = 1; off < 64; off <<= 1) { int y = __shfl_up(x, off); if (lane >= off) x += y; }
  __shared__ int wsum[4];
  if (lane == 63) wsum[w] = x;
  __syncthreads();
  int wadd = 0;
  for (int i = 0; i < w; ++i) wadd += wsum[i];
  int run = blkoff[b] + wadd + x - s;
#pragma unroll
  for (int k = 0; k < 4; ++k) {
    if (base + k < n) { rowptr[base + k] = run; cursor[base + k] = run; }
    run += v[k];
  }
  if (n >= base && n <= base + 4) rowptr[n] = run;
}

__global__ void k_scatter(const int* __restrict__ src, const int* __restrict__ dst,
    int* __restrict__ cursor, int* __restrict__ esrc, int E) {
  int e = blockIdx.x * 256 + threadIdx.x;
  if (e < E) {
    int p = atomicAdd(&cursor[dst[e]], 1);
    esrc[p] = src[e];
  }
}

// ---------------- 64x64-tile transpose: W2T = W2^T, W3T = W3^T ----------------
__global__ __launch_bounds__(256) void k_tr2(const float* __restrict__ W2,
    const float* __restrict__ W3, float* __restrict__ W2T, float* __restrict__ W3T) {
  __shared__ float tile[64][65];
  const float* src = blockIdx.z ? W3 : W2;
  float* dst = blockIdx.z ? W3T : W2T;
  int i0 = blockIdx.x * 64, j0 = blockIdx.y * 64;
  int tx = threadIdx.x & 63, ty = threadIdx.x >> 6;
#pragma unroll
  for (int m = 0; m < 16; ++m) {
    int r = ty * 16 + m;
    tile[r][tx] = src[(size_t)(i0 + r) * 256 + j0 + tx];
  }
  __syncthreads();
#pragma unroll
  for (int m = 0; m < 16; ++m) {
    int r = ty * 16 + m;
    dst[(size_t)(j0 + r) * 256 + i0 + tx] = tile[tx][r];
  }
}

// ---------------- feature aggregation (proven; DO NOT TOUCH — the control) ----------------
__global__ __launch_bounds__(256) void k_agg(const float* __restrict__ h,
    const int* __restrict__ rowptr, const int* __restrict__ esrc,
    float* __restrict__ out, int n) {
  int wid = ((blockIdx.x * 256) + threadIdx.x) >> 6;
  int lane = threadIdx.x & 63;
  if (wid >= n) return;
  int beg = rowptr[wid], end = rowptr[wid + 1];
  const float4* hv = (const float4*)h;
  float4 a0 = {0,0,0,0}, a1 = {0,0,0,0}, a2 = {0,0,0,0}, a3 = {0,0,0,0};
  int e = beg;
  for (; e + 4 <= end; e += 4) {
    int s0 = esrc[e], s1 = esrc[e + 1], s2 = esrc[e + 2], s3 = esrc[e + 3];
    float4 v0 = hv[(size_t)s0 * 64 + lane];
    float4 v1 = hv[(size_t)s1 * 64 + lane];
    float4 v2 = hv[(size_t)s2 * 64 + lane];
    float4 v3 = hv[(size_t)s3 * 64 + lane];
    a0.x += v0.x; a0.y += v0.y; a0.z += v0.z; a0.w += v0.w;
    a1.x += v1.x; a1.y += v1.y; a1.z += v1.z; a1.w += v1.w;
    a2.x += v2.x; a2.y += v2.y; a2.z += v2.z; a2.w += v2.w;
    a3.x += v3.x; a3.y += v3.y; a3.z += v3.z; a3.w += v3.w;
  }
  for (; e < end; ++e) {
    float4 v = hv[(size_t)esrc[e] * 64 + lane];
    a0.x += v.x; a0.y += v.y; a0.z += v.z; a0.w += v.w;
  }
  float4 r;
  r.x = (a0.x + a1.x) + (a2.x + a3.x);
  r.y = (a0.y + a1.y) + (a2.y + a3.y);
  r.z = (a0.z + a1.z) + (a2.z + a3.z);
  r.w = (a0.w + a1.w) + (a2.w + a3.w);
  ((float4*)out)[(size_t)wid * 64 + lane] = r;
}

// ---------------- dual-graph scalar aggregation, 16 lanes/node, deg inlined ----------------
__global__ __launch_bounds__(256) void k_aggv2(const float* __restrict__ in1,
    const float* __restrict__ in2,
    const int* __restrict__ rp1, const int* __restrict__ es1,
    const int* __restrict__ rp2, const int* __restrict__ es2,
    float* __restrict__ out1, float* __restrict__ out2, int n, int useDeg) {
  int t = blockIdx.x * 256 + threadIdx.x;
  int g = t >> 4;
  int sl = t & 15;
  if (g >= 2 * n) return;
  int which = (g >= n) ? 1 : 0;
  int node = which ? g - n : g;
  const int* rp = which ? rp2 : rp1;
  const int* es = which ? es2 : es1;
  const float* in = which ? in2 : in1;
  float* out = which ? out2 : out1;
  int beg = rp[node], end = rp[node + 1];
  float s = 0.f;
  if (useDeg) {
    for (int e = beg + sl; e < end; e += 16) {
      int v = es[e];
      s += (float)(rp[v + 1] - rp[v]);
    }
  } else {
    for (int e = beg + sl; e < end; e += 16) s += in[es[e]];
  }
#pragma unroll
  for (int off = 8; off; off >>= 1) s += __shfl_down(s, off, 16);
  if (sl == 0) out[node] = s;
}

// ---------------- symmetric Gram (X^T X): tiles (0,0),(0,1),(1,1); diag reads X once ----
// Fused colsum of X on diagonal tiles -> mc[256].
__global__ __launch_bounds__(256) void k_gram_sym(const float* __restrict__ Xm,
    float* __restrict__ partial, int N, float* __restrict__ mc) {
  __shared__ float Xs[16][132];
  __shared__ float Ys[16][132];
  int tid = threadIdx.x;
  int t = blockIdx.x;                       // 0:(0,0) 1:(0,1) 2:(1,1)
  int i0 = (t == 2) ? 128 : 0;
  int j0 = (t == 0) ? 0 : 128;
  bool diag = (t != 1);
  int z = blockIdx.z;
  int chunk = (N + GRAM_KS - 1) / GRAM_KS;
  int rb = z * chunk, re = min(N, rb + chunk);
  int lk = tid >> 4;
  int tj = tid & 15;
  int lc = tj * 8;
  int ti = lk;
  int cc = tid & 127, hh = tid >> 7;
  float xP = 0.f;
  float (*Yr)[132] = diag ? Xs : Ys;
  float acc[8][8] = {};
  for (int rr = rb; rr < re; rr += 16) {
    int r = rr + lk;
    float4 a0 = {0,0,0,0}, a1 = {0,0,0,0}, b0 = {0,0,0,0}, b1 = {0,0,0,0};
    if (r < re) {
      const float* xp = Xm + (size_t)r * 256 + i0 + lc;
      a0 = *(const float4*)xp; a1 = *(const float4*)(xp + 4);
      if (!diag) {
        const float* yp = Xm + (size_t)r * 256 + j0 + lc;
        b0 = *(const float4*)yp; b1 = *(const float4*)(yp + 4);
      }
    }
    *(float4*)&Xs[lk][lc] = a0; *(float4*)&Xs[lk][lc + 4] = a1;
    if (!diag) { *(float4*)&Ys[lk][lc] = b0; *(float4*)&Ys[lk][lc + 4] = b1; }
    __syncthreads();
    if (diag && mc) {
#pragma unroll
      for (int k = 0; k < 8; ++k) xP += Xs[hh * 8 + k][cc];
    }
#pragma unroll
    for (int k = 0; k < 16; ++k) {
      float av[8], bv[8];
      *(float4*)&av[0] = *(const float4*)&Xs[k][ti * 4];
      *(float4*)&av[4] = *(const float4*)&Xs[k][64 + ti * 4];
      *(float4*)&bv[0] = *(const float4*)&Yr[k][tj * 4];
      *(float4*)&bv[4] = *(const float4*)&Yr[k][64 + tj * 4];
#pragma unroll
      for (int i = 0; i < 8; ++i)
#pragma unroll
        for (int j = 0; j < 8; ++j) acc[i][j] += av[i] * bv[j];
    }
    __syncthreads();
  }
  float* pout = partial + (size_t)z * 65536;
#pragma unroll
  for (int i = 0; i < 8; ++i) {
    int row = i0 + ((i < 4) ? (ti * 4 + i) : (64 + ti * 4 + i - 4));
#pragma unroll
    for (int j = 0; j < 8; j += 4) {
      int col = j0 + ((j < 4) ? (tj * 4 + j) : (64 + tj * 4 + j - 4));
      *(float4*)(pout + (size_t)row * 256 + col) = *(float4*)&acc[i][j];
    }
  }
  if (diag && mc) {
    __syncthreads();
    Xs[hh][cc] = xP;
    __syncthreads();
    if (tid < 128) atomicAdd(&mc[i0 + tid], Xs[0][tid] + Xs[1][tid]);
  }
}

__global__ void k_gram_reduce_sym(const float* __restrict__ partial, float* __restrict__ C) {
  int idx = blockIdx.x * 256 + threadIdx.x;
  int i = idx >> 8, j = idx & 255;
  int sidx = (i >= 128 && j < 128) ? (j * 256 + i) : idx;   // mirror from (0,1) tile
  float s = 0.f;
  for (int z = 0; z < GRAM_KS; ++z) s += partial[(size_t)z * 65536 + sidx];
  C[idx] = s;
}

// ---------------- general Gram + fused weighted column sums (final Z) ----------------
__global__ __launch_bounds__(256) void k_gram(const float* __restrict__ Xm,
    const float* __restrict__ Ym, float* __restrict__ partial, int N,
    const float* __restrict__ wxA, const float* __restrict__ wxB, float* __restrict__ outX,
    const float* __restrict__ wyA, const float* __restrict__ wyB, float* __restrict__ outY) {
  __shared__ float Xs[16][132];
  __shared__ float Ys[16][132];
  __shared__ float wls[4][16];
  int tid = threadIdx.x;
  int i0 = blockIdx.x * 128, j0 = blockIdx.y * 128;
  int z = blockIdx.z;
  int chunk = (N + GRAM_KS - 1) / GRAM_KS;
  int rb = z * chunk, re = min(N, rb + chunk);
  int lk = tid >> 4;
  int tj = tid & 15;
  int lc = tj * 8;
  int ti = lk;
  bool doX = (outX != nullptr) && (blockIdx.y == 0);
  bool doY = (outY != nullptr) && (blockIdx.x == 0);
  int cc = tid & 127, hh = tid >> 7;
  float xA = 0, xB = 0, xP = 0, yA = 0, yB = 0, yP = 0;
  float acc[8][8] = {};
  for (int rr = rb; rr < re; rr += 16) {
    int r = rr + lk;
    float4 a0 = {0,0,0,0}, a1 = {0,0,0,0}, b0 = {0,0,0,0}, b1 = {0,0,0,0};
    if (r < re) {
      const float* xp = Xm + (size_t)r * 256 + i0 + lc;
      const float* yp = Ym + (size_t)r * 256 + j0 + lc;
      a0 = *(const float4*)xp; a1 = *(const float4*)(xp + 4);
      b0 = *(const float4*)yp; b1 = *(const float4*)(yp + 4);
    }
    *(float4*)&Xs[lk][lc] = a0; *(float4*)&Xs[lk][lc + 4] = a1;
    *(float4*)&Ys[lk][lc] = b0; *(float4*)&Ys[lk][lc + 4] = b1;
    if (tid < 64) {
      int grp = tid >> 4, kk = tid & 15, rw = rr + kk;
      const float* wp = (grp == 0) ? wxA : (grp == 1) ? wxB : (grp == 2) ? wyA : wyB;
      wls[grp][kk] = (wp && rw < re) ? wp[rw] : 0.f;
    }
    __syncthreads();
    if (doX) {
#pragma unroll
      for (int k = 0; k < 8; ++k) {
        float v = Xs[hh * 8 + k][cc];
        xP += v; xA += v * wls[0][hh * 8 + k]; xB += v * wls[1][hh * 8 + k];
      }
    }
    if (doY) {
#pragma unroll
      for (int k = 0; k < 8; ++k) {
        float v = Ys[hh * 8 + k][cc];
        yP += v; yA += v * wls[2][hh * 8 + k]; yB += v * wls[3][hh * 8 + k];
      }
    }
#pragma unroll
    for (int k = 0; k < 16; ++k) {
      float av[8], bv[8];
      *(float4*)&av[0] = *(const float4*)&Xs[k][ti * 4];
      *(float4*)&av[4] = *(const float4*)&Xs[k][64 + ti * 4];
      *(float4*)&bv[0] = *(const float4*)&Ys[k][tj * 4];
      *(float4*)&bv[4] = *(const float4*)&Ys[k][64 + tj * 4];
#pragma unroll
      for (int i = 0; i < 8; ++i)
#pragma unroll
        for (int j = 0; j < 8; ++j) acc[i][j] += av[i] * bv[j];
    }
    __syncthreads();
  }
  float* pout = partial + (size_t)z * 65536;
#pragma unroll
  for (int i = 0; i < 8; ++i) {
    int row = i0 + ((i < 4) ? (ti * 4 + i) : (64 + ti * 4 + i - 4));
#pragma unroll
    for (int j = 0; j < 8; j += 4) {
      int col = j0 + ((j < 4) ? (tj * 4 + j) : (64 + tj * 4 + j - 4));
      *(float4*)(pout + (size_t)row * 256 + col) = *(float4*)&acc[i][j];
    }
  }
  if (doX) {
    __syncthreads();
    Xs[hh][cc] = xA;
    __syncthreads();
    if (tid < 128) atomicAdd(&outX[i0 + tid], Xs[0][tid] + Xs[1][tid]);
    __syncthreads();
    Xs[hh][cc] = xB;
    __syncthreads();
    if (tid < 128) atomicAdd(&outX[256 + i0 + tid], Xs[0][tid] + Xs[1][tid]);
    __syncthreads();
    Xs[hh][cc] = xP;
    __syncthreads();
    if (tid < 128) atomicAdd(&outX[512 + i0 + tid], Xs[0][tid] + Xs[1][tid]);
  }
  if (doY) {
    __syncthreads();
    Ys[hh][cc] = yA;
    __syncthreads();
    if (tid < 128) atomicAdd(&outY[j0 + tid], Ys[0][tid] + Ys[1][tid]);
    __syncthreads();
    Ys[hh][cc] = yB;
    __syncthreads();
    if (tid < 128) atomicAdd(&outY[256 + j0 + tid], Ys[0][tid] + Ys[1][tid]);
    __syncthreads();
    Ys[hh][cc] = yP;
    __syncthreads();
    if (tid < 128) atomicAdd(&outY[512 + j0 + tid], Ys[0][tid] + Ys[1][tid]);
  }
}

__global__ void k_gram_reduce(const float* __restrict__ partial, float* __restrict__ C) {
  int idx = blockIdx.x * 256 + threadIdx.x;
  float s = 0.f;
  for (int z = 0; z < GRAM_KS; ++z) s += partial[(size_t)z * 65536 + idx];
  C[idx] = s;
}

// ---------------- 8 scalar reductions over d/e vectors ----------------
__global__ __launch_bounds__(256) void k_dots(const float* __restrict__ d1,
    const float* __restrict__ e1, const float* __restrict__ d2,
    const float* __restrict__ e2, float* scal, int n) {
  int i = blockIdx.x * 256 + threadIdx.x;
  float a = 0, b = 0, c = 0, d = 0;
  if (i < n) { a = d1[i]; b = e1[i]; c = d2[i]; d = e2[i]; }
  float v[8] = { b * d, b * c, b, a * d, a * c, a, d, c };
#pragma unroll
  for (int j = 0; j < 8; ++j) {
    float x = v[j];
    for (int off = 32; off; off >>= 1) x += __shfl_down(x, off);
    v[j] = x;
  }
  if ((threadIdx.x & 63) == 0)
#pragma unroll
    for (int j = 0; j < 8; ++j) atomicAdd(&scal[j], v[j]);
}

// ---------------- t_j = w_j^T C w_j ; mv_j = w_j . m_raw ----------------
__global__ __launch_bounds__(256) void k_quad(const float* __restrict__ C,
    const float* __restrict__ W1, const float* __restrict__ m_raw,
    float* __restrict__ t, float* __restrict__ mv) {
  __shared__ float w[256];
  __shared__ float r1[256], r2[256];
  int j = blockIdx.x, tid = threadIdx.x;
  w[tid] = W1[j * 256 + tid];
  __syncthreads();
  float v = 0.f;
  for (int k = 0; k < 256; ++k) v += w[k] * C[k * 256 + tid];
  r1[tid] = v * w[tid];
  r2[tid] = w[tid] * m_raw[tid];
  __syncthreads();
  for (int off = 128; off; off >>= 1) {
    if (tid < off) { r1[tid] += r1[tid + off]; r2[tid] += r2[tid + off]; }
    __syncthreads();
  }
  if (tid == 0) { t[j] = r1[0]; mv[j] = r2[0]; }
}

// ---------------- BN coefficients (coalesced via W2T/W3T) ----------------
__global__ __launch_bounds__(256) void k_bncoef(const float* __restrict__ t,
    const float* __restrict__ mv, const float* __restrict__ b1,
    const float* __restrict__ gamma, const float* __restrict__ beta,
    const float* __restrict__ W2T, const float* __restrict__ W3T,
    const float* __restrict__ b2, float* Dv, float* xv, float* yv, int n) {
  __shared__ float c[256], u[256];
  int j = threadIdx.x;
  float invn = 1.f / (float)n;
  float mean = mv[j] * invn + b1[j];
  float E2 = t[j] * invn + 2.f * b1[j] * mv[j] * invn + b1[j] * b1[j];
  float var = E2 - mean * mean;
  float D = gamma[j] * rsqrtf(var + 1e-5f);
  Dv[j] = D;
  c[j] = D * (b1[j] - mean) + beta[j];
  __syncthreads();
  float uu = 0.f;
  for (int k = 0; k < 256; ++k) uu += W2T[k * 256 + j] * c[k];
  u[j] = uu;
  __syncthreads();
  float xx = 0.f, yy = 0.f;
  for (int k = 0; k < 256; ++k) {
    xx += W3T[k * 256 + j] * u[k];
    yy += W3T[k * 256 + j] * b2[k];
  }
  xv[j] = xx;
  yv[j] = yy;
}

// ---------------- small 256x256 matmul (B always coalesced: B[k][j]) ----------------
__global__ __launch_bounds__(256) void k_mm_small(float* __restrict__ Cm,
    const float* __restrict__ A, const float* __restrict__ B,
    const float* __restrict__ s, int transA) {
  __shared__ float a[256];
  int i = blockIdx.x, j = threadIdx.x;
  float av = transA ? A[j * 256 + i] : A[i * 256 + j];
  a[j] = s ? av * s[j] : av;
  __syncthreads();
  float acc = 0.f;
  for (int k = 0; k < 256; ++k) acc += a[k] * B[k * 256 + j];
  Cm[i * 256 + j] = acc;
}

// ---------------- 6 matvecs: vout[b] = M_b^T w_b ----------------
__global__ __launch_bounds__(256) void k_mv6(const float* __restrict__ R1,
    const float* __restrict__ R2, const float* __restrict__ pX,
    const float* __restrict__ qY, float* __restrict__ vout) {
  __shared__ float w[256];
  int b = blockIdx.x, j = threadIdx.x;
  const float* M = (b < 3) ? R1 : R2;
  const float* wv = (b < 3) ? (pX + b * 256) : (qY + (b - 3) * 256);
  w[j] = wv[j];
  __syncthreads();
  float s = 0.f;
  for (int k = 0; k < 256; ++k) s += M[k * 256 + j] * w[k];
  vout[b * 256 + j] = s;
}

// ---------------- final: out = R1^T T1 + 6 rank-1 terms ----------------
__global__ __launch_bounds__(256) void k_mm_final(float* __restrict__ out,
    const float* __restrict__ R1, const float* __restrict__ T1,
    const float* __restrict__ vout,   // v1|v2|v3|u1|u2|u3
    const float* __restrict__ x1, const float* __restrict__ x2,
    const float* __restrict__ yv, const float* __restrict__ b3,
    const float* __restrict__ scal, float fN) {
  __shared__ float a[256];
  int i = blockIdx.x, j = threadIdx.x;
  a[j] = R1[j * 256 + i];
  __syncthreads();
  float acc = 0.f;
  for (int k = 0; k < 256; ++k) acc += a[k] * T1[k * 256 + j];
  float s1 = scal[0] * x2[j] + scal[1] * yv[j] + scal[2] * b3[j];
  float s2 = scal[3] * x2[j] + scal[4] * yv[j] + scal[5] * b3[j];
  float s3 = scal[6] * x2[j] + scal[7] * yv[j] + fN * b3[j];
  acc += vout[i] * x2[j] + vout[256 + i] * yv[j] + vout[512 + i] * b3[j];
  acc += x1[i] * (vout[768 + j] + s1) + yv[i] * (vout[1024 + j] + s2)
       + b3[i] * (vout[1280 + j] + s3);
  out[i * 256 + j] = acc;
}

extern "C" void kernel_launch(void* const* d_in, const int* in_sizes, int n_in,
                              void* d_out, int out_size, void* d_ws, size_t ws_size,
                              hipStream_t stream) {
  const float* feature = (const float*)d_in[0];
  const int* src1 = (const int*)d_in[1];
  const int* dst1 = (const int*)d_in[2];
  const int* src2 = (const int*)d_in[3];
  const int* dst2 = (const int*)d_in[4];
  const float* W1 = (const float*)d_in[5];
  const float* b1 = (const float*)d_in[6];
  const float* W2 = (const float*)d_in[7];
  const float* b2 = (const float*)d_in[8];
  const float* W3 = (const float*)d_in[9];
  const float* b3 = (const float*)d_in[10];
  const float* gamma = (const float*)d_in[11];
  const float* beta = (const float*)d_in[12];
  const int N = in_sizes[0] / FDIM;
  const int E = in_sizes[1];
  float* out = (float*)d_out;

  // ---- workspace layout ----
  float* X = (float*)d_ws;
  size_t NF = (size_t)N * FDIM;
  float* Y = X + NF;
  float* G2A = Y + NF;
  int* rowptr1 = (int*)(G2A + NF);
  int* rowptr2 = rowptr1 + (N + 1);
  int* cursor = rowptr2 + (N + 1);
  int* esrc1 = cursor + N;
  int* esrc2 = esrc1 + E;
  float* vtmp1 = (float*)(esrc2 + E);
  float* vtmp2 = vtmp1 + N;
  float* d1 = vtmp2 + N; float* e1 = d1 + N; float* d2 = e1 + N; float* e2 = d2 + N;
  float* C = e2 + N;
  // zeroed accumulator span (contiguous): mcA(256) mcB(256) pX(768) qY(768) scal(16)
  float* mcA = C + 65536;
  float* mcB = mcA + 256;
  float* pX = mcB + 256;
  float* qY = pX + 768;
  float* scal = qY + 768;
  // non-zeroed small:
  float* tq = scal + 16; float* mv = tq + 256;
  float* Dv = mv + 256; float* x1 = Dv + 256; float* x2 = x1 + 256; float* yv = x2 + 256;
  float* Q = yv + 256; float* R1 = Q + 65536; float* R2 = R1 + 65536;
  float* Z = R2 + 65536; float* T1 = Z + 65536;
  float* W2T = T1 + 65536; float* W3T = W2T + 65536;
  float* vout = W3T + 65536;          // 6*256
  int* blksum = (int*)(vout + 1536);
  int* blkoff = blksum + 1024;
  float* partial = X;   // GRAM_KS*65536 = 12.58M floats <= NF (12.8M); X dead at gram time

  const int eb = (E + 255) / 256;
  const int nb = (N + 255) / 256;
  const int aggb = (N + 3) / 4;
  const int avb2 = (2 * N * 16 + 255) / 256;
  const int nblk = (N + 1023) / 1024;

  auto build = [&](const int* s_, const int* d_, int* rp, int* es) {
    hipMemsetAsync(cursor, 0, (size_t)N * sizeof(int), stream);
    k_hist<<<eb, 256, 0, stream>>>(d_, cursor, E);
    k_blksum<<<nblk, 256, 0, stream>>>(cursor, blksum, N);
    k_blkscan<<<1, 64, 0, stream>>>(blksum, blkoff, nblk);
    k_scan_blk<<<nblk, 256, 0, stream>>>(cursor, blkoff, rp, cursor, N);
    k_scatter<<<eb, 256, 0, stream>>>(s_, d_, cursor, es, E);
  };

  k_tr2<<<dim3(4, 4, 2), 256, 0, stream>>>(W2, W3, W2T, W3T);
  build(src1, dst1, rowptr1, esrc1);
  build(src2, dst2, rowptr2, esrc2);
  hipMemsetAsync(mcA, 0, (256 * 2 + 768 * 2 + 16) * sizeof(float), stream);

  // ---- d/e vectors for both graphs ----
  k_aggv2<<<avb2, 256, 0, stream>>>(nullptr, nullptr, rowptr1, esrc1, rowptr2, esrc2,
                                    d1, d2, N, 1);
  k_aggv2<<<avb2, 256, 0, stream>>>(d1, d2, rowptr1, esrc1, rowptr2, esrc2,
                                    vtmp1, vtmp2, N, 0);
  k_aggv2<<<avb2, 256, 0, stream>>>(vtmp1, vtmp2, rowptr1, esrc1, rowptr2, esrc2,
                                    e1, e2, N, 0);
  k_dots<<<nb, 256, 0, stream>>>(d1, e1, d2, e2, scal, N);

  auto do_branch = [&](const int* rp, const int* es, float* G2dst,
                       float* mc, float* xvec, float* Rdst) {
    k_agg<<<aggb, 256, 0, stream>>>(feature, rp, es, X, N);
    k_agg<<<aggb, 256, 0, stream>>>(X, rp, es, Y, N);                 // Y = G0
    k_gram_sym<<<dim3(3, 1, GRAM_KS), 256, 0, stream>>>(Y, partial, N, mc);
    k_gram_reduce_sym<<<256, 256, 0, stream>>>(partial, C);           // C = G0^T G0
    k_quad<<<256, 256, 0, stream>>>(C, W1, mc, tq, mv);
    k_bncoef<<<1, 256, 0, stream>>>(tq, mv, b1, gamma, beta, W2T, W3T, b2, Dv, xvec, yv, N);
    k_mm_small<<<256, 256, 0, stream>>>(Q, W1, W2T, Dv, 1);           // Q = W1^T D W2^T
    k_mm_small<<<256, 256, 0, stream>>>(Rdst, Q, W3T, nullptr, 0);    // R = Q W3^T
    k_agg<<<aggb, 256, 0, stream>>>(Y, rp, es, X, N);
    k_agg<<<aggb, 256, 0, stream>>>(X, rp, es, Y, N);                 // A^4 F
    k_agg<<<aggb, 256, 0, stream>>>(Y, rp, es, X, N);
    k_agg<<<aggb, 256, 0, stream>>>(X, rp, es, G2dst, N);             // G2 = A^6 F
  };

  do_branch(rowptr1, esrc1, G2A, mcA, x1, R1);
  do_branch(rowptr2, esrc2, Y, mcB, x2, R2);    // branch-2 G2 lands in Y

  // ---- final: Z = G2_1^T G2_2 with fused weighted colsums ----
  k_gram<<<dim3(2, 2, GRAM_KS), 256, 0, stream>>>(G2A, Y, partial, N,
      e2, d2, pX, e1, d1, qY);
  k_gram_reduce<<<256, 256, 0, stream>>>(partial, Z);

  k_mm_small<<<256, 256, 0, stream>>>(T1, Z, R2, nullptr, 0);         // T1 = Z R2
  k_mv6<<<6, 256, 0, stream>>>(R1, R2, pX, qY, vout);
  k_mm_final<<<256, 256, 0, stream>>>(out, R1, T1, vout, x1, x2, yv, b3, scal, (float)N);
}

// Round 11
// 1560.705 us; speedup vs baseline: 1.4334x; 1.4334x over previous
//
#include <hip/hip_runtime.h>
#include <hip/hip_fp16.h>

#define FDIM 256
#define GRAM_KS 192

// scaled-fp16 storage: hop h stored = true * 4^-h. Rescales (exact powers of 2):
//   C = G0^T G0: *256 ; Z = G2^T G2: *2^24 ; G2 colsums: *4096 ; G0 colsum: *16

__device__ __forceinline__ void h4acc(uint2 u, float4& a) {
  float2 f0 = __half22float2(*(__half2*)&u.x);
  float2 f1 = __half22float2(*(__half2*)&u.y);
  a.x += f0.x; a.y += f0.y; a.z += f1.x; a.w += f1.y;
}

__device__ __forceinline__ void h8f(uint4 u, float* f) {
  float2 t;
  t = __half22float2(*(__half2*)&u.x); f[0] = t.x; f[1] = t.y;
  t = __half22float2(*(__half2*)&u.y); f[2] = t.x; f[3] = t.y;
  t = __half22float2(*(__half2*)&u.z); f[4] = t.x; f[5] = t.y;
  t = __half22float2(*(__half2*)&u.w); f[6] = t.x; f[7] = t.y;
}

// ---------------- CSR build ----------------
__global__ void k_hist(const int* __restrict__ dst, int* __restrict__ deg, int E) {
  int e = blockIdx.x * 256 + threadIdx.x;
  if (e < E) atomicAdd(&deg[dst[e]], 1);
}

__global__ __launch_bounds__(256) void k_blksum(const int* __restrict__ deg,
    int* __restrict__ blksum, int n) {
  int b = blockIdx.x, tid = threadIdx.x;
  int base = b * 1024 + tid * 4;
  int s = 0;
#pragma unroll
  for (int k = 0; k < 4; ++k) if (base + k < n) s += deg[base + k];
  for (int off = 32; off; off >>= 1) s += __shfl_down(s, off);
  __shared__ int ws4[4];
  if ((tid & 63) == 0) ws4[tid >> 6] = s;
  __syncthreads();
  if (tid == 0) blksum[b] = ws4[0] + ws4[1] + ws4[2] + ws4[3];
}

__global__ void k_blkscan(const int* __restrict__ blksum, int* __restrict__ blkoff, int nblk) {
  int lane = threadIdx.x;
  int carry = 0;
  for (int base = 0; base < nblk; base += 64) {
    int v = (base + lane < nblk) ? blksum[base + lane] : 0;
    int x = v;
    for (int off = 1; off < 64; off <<= 1) { int y = __shfl_up(x, off); if (lane >= off) x += y; }
    if (base + lane < nblk) blkoff[base + lane] = carry + x - v;
    carry += __shfl(x, 63);
  }
}

__global__ __launch_bounds__(256) void k_scan_blk(const int* __restrict__ deg,
    const int* __restrict__ blkoff, int* __restrict__ rowptr, int* __restrict__ cursor, int n) {
  int b = blockIdx.x, tid = threadIdx.x;
  int base = b * 1024 + tid * 4;
  int v[4];
#pragma unroll
  for (int k = 0; k < 4; ++k) v[k] = (base + k < n) ? deg[base + k] : 0;
  int s = v[0] + v[1] + v[2] + v[3];
  int lane = tid & 63, w = tid >> 6;
  int x = s;
  for (int off = 1; off < 64; off <<= 1) { int y = __shfl_up(x, off); if (lane >= off) x += y; }
  __shared__ int wsum[4];
  if (lane == 63) wsum[w] = x;
  __syncthreads();
  int wadd = 0;
  for (int i = 0; i < w; ++i) wadd += wsum[i];
  int run = blkoff[b] + wadd + x - s;
#pragma unroll
  for (int k = 0; k < 4; ++k) {
    if (base + k < n) { rowptr[base + k] = run; cursor[base + k] = run; }
    run += v[k];
  }
  if (n >= base && n <= base + 4) rowptr[n] = run;
}

__global__ void k_scatter(const int* __restrict__ src, const int* __restrict__ dst,
    int* __restrict__ cursor, int* __restrict__ esrc, int E) {
  int e = blockIdx.x * 256 + threadIdx.x;
  if (e < E) {
    int p = atomicAdd(&cursor[dst[e]], 1);
    esrc[p] = src[e];
  }
}

// ---------------- transpose W2,W3 ----------------
__global__ __launch_bounds__(256) void k_tr2(const float* __restrict__ W2,
    const float* __restrict__ W3, float* __restrict__ W2T, float* __restrict__ W3T) {
  __shared__ float tile[64][65];
  const float* src = blockIdx.z ? W3 : W2;
  float* dst = blockIdx.z ? W3T : W2T;
  int i0 = blockIdx.x * 64, j0 = blockIdx.y * 64;
  int tx = threadIdx.x & 63, ty = threadIdx.x >> 6;
#pragma unroll
  for (int m = 0; m < 16; ++m) {
    int r = ty * 16 + m;
    tile[r][tx] = src[(size_t)(i0 + r) * 256 + j0 + tx];
  }
  __syncthreads();
#pragma unroll
  for (int m = 0; m < 16; ++m) {
    int r = ty * 16 + m;
    dst[(size_t)(j0 + r) * 256 + i0 + tx] = tile[tx][r];
  }
}

// ---------------- feature -> fp16 ----------------
__global__ __launch_bounds__(256) void k_f2h(const float* __restrict__ F,
    __half* __restrict__ H, int n4) {
  int i = blockIdx.x * 256 + threadIdx.x;
  if (i >= n4) return;
  float4 v = ((const float4*)F)[i];
  __half2 a = __floats2half2_rn(v.x, v.y);
  __half2 b = __floats2half2_rn(v.z, v.w);
  uint2 u; u.x = *(unsigned int*)&a; u.y = *(unsigned int*)&b;
  ((uint2*)H)[i] = u;
}

// ---------------- fp16 aggregation: one wave/node, one-shot, unroll-4, out = sum/4 ----
__global__ __launch_bounds__(256) void k_aggh(const __half* __restrict__ h,
    const int* __restrict__ rowptr, const int* __restrict__ esrc,
    __half* __restrict__ out, int n) {
  int wid = ((blockIdx.x * 256) + threadIdx.x) >> 6;
  int lane = threadIdx.x & 63;
  if (wid >= n) return;
  int beg = rowptr[wid], end = rowptr[wid + 1];
  const uint2* hv = (const uint2*)h;     // row = 64 x uint2 (4 halves each)
  float4 a0 = {0,0,0,0}, a1 = {0,0,0,0}, a2 = {0,0,0,0}, a3 = {0,0,0,0};
  int e = beg;
  for (; e + 4 <= end; e += 4) {
    int s0 = esrc[e], s1 = esrc[e + 1], s2 = esrc[e + 2], s3 = esrc[e + 3];
    uint2 u0 = hv[(size_t)s0 * 64 + lane];
    uint2 u1 = hv[(size_t)s1 * 64 + lane];
    uint2 u2 = hv[(size_t)s2 * 64 + lane];
    uint2 u3 = hv[(size_t)s3 * 64 + lane];
    h4acc(u0, a0); h4acc(u1, a1); h4acc(u2, a2); h4acc(u3, a3);
  }
  for (; e < end; ++e) {
    uint2 u = hv[(size_t)esrc[e] * 64 + lane];
    h4acc(u, a0);
  }
  float4 r;
  r.x = ((a0.x + a1.x) + (a2.x + a3.x)) * 0.25f;
  r.y = ((a0.y + a1.y) + (a2.y + a3.y)) * 0.25f;
  r.z = ((a0.z + a1.z) + (a2.z + a3.z)) * 0.25f;
  r.w = ((a0.w + a1.w) + (a2.w + a3.w)) * 0.25f;
  __half2 ha = __floats2half2_rn(r.x, r.y);
  __half2 hb = __floats2half2_rn(r.z, r.w);
  uint2 uo; uo.x = *(unsigned int*)&ha; uo.y = *(unsigned int*)&hb;
  ((uint2*)out)[(size_t)wid * 64 + lane] = uo;
}

// ---------------- dual-graph scalar aggregation (fp32, exact) ----------------
__global__ __launch_bounds__(256) void k_aggv2(const float* __restrict__ in1,
    const float* __restrict__ in2,
    const int* __restrict__ rp1, const int* __restrict__ es1,
    const int* __restrict__ rp2, const int* __restrict__ es2,
    float* __restrict__ out1, float* __restrict__ out2, int n, int useDeg) {
  int t = blockIdx.x * 256 + threadIdx.x;
  int g = t >> 4;
  int sl = t & 15;
  if (g >= 2 * n) return;
  int which = (g >= n) ? 1 : 0;
  int node = which ? g - n : g;
  const int* rp = which ? rp2 : rp1;
  const int* es = which ? es2 : es1;
  const float* in = which ? in2 : in1;
  float* out = which ? out2 : out1;
  int beg = rp[node], end = rp[node + 1];
  float s = 0.f;
  if (useDeg) {
    for (int e = beg + sl; e < end; e += 16) {
      int v = es[e];
      s += (float)(rp[v + 1] - rp[v]);
    }
  } else {
    for (int e = beg + sl; e < end; e += 16) s += in[es[e]];
  }
#pragma unroll
  for (int off = 8; off; off >>= 1) s += __shfl_down(s, off, 16);
  if (sl == 0) out[node] = s;
}

// ---------------- symmetric Gram on fp16 input ----------------
__global__ __launch_bounds__(256) void k_gram_sym(const __half* __restrict__ Xm,
    float* __restrict__ partial, int N, float* __restrict__ mc) {
  __shared__ float Xs[16][132];
  __shared__ float Ys[16][132];
  int tid = threadIdx.x;
  int t = blockIdx.x;                       // 0:(0,0) 1:(0,1) 2:(1,1)
  int i0 = (t == 2) ? 128 : 0;
  int j0 = (t == 0) ? 0 : 128;
  bool diag = (t != 1);
  int z = blockIdx.z;
  int chunk = (N + GRAM_KS - 1) / GRAM_KS;
  int rb = z * chunk, re = min(N, rb + chunk);
  int lk = tid >> 4;
  int tj = tid & 15;
  int lc = tj * 8;
  int ti = lk;
  int cc = tid & 127, hh = tid >> 7;
  float xP = 0.f;
  float (*Yr)[132] = diag ? Xs : Ys;
  float acc[8][8] = {};
  for (int rr = rb; rr < re; rr += 16) {
    int r = rr + lk;
    float fx[8] = {}, fy[8] = {};
    if (r < re) {
      uint4 u = *(const uint4*)(Xm + (size_t)r * 256 + i0 + lc);
      h8f(u, fx);
      if (!diag) {
        uint4 v = *(const uint4*)(Xm + (size_t)r * 256 + j0 + lc);
        h8f(v, fy);
      }
    }
    *(float4*)&Xs[lk][lc] = *(float4*)&fx[0];
    *(float4*)&Xs[lk][lc + 4] = *(float4*)&fx[4];
    if (!diag) {
      *(float4*)&Ys[lk][lc] = *(float4*)&fy[0];
      *(float4*)&Ys[lk][lc + 4] = *(float4*)&fy[4];
    }
    __syncthreads();
    if (diag && mc) {
#pragma unroll
      for (int k = 0; k < 8; ++k) xP += Xs[hh * 8 + k][cc];
    }
#pragma unroll
    for (int k = 0; k < 16; ++k) {
      float av[8], bv[8];
      *(float4*)&av[0] = *(const float4*)&Xs[k][ti * 4];
      *(float4*)&av[4] = *(const float4*)&Xs[k][64 + ti * 4];
      *(float4*)&bv[0] = *(const float4*)&Yr[k][tj * 4];
      *(float4*)&bv[4] = *(const float4*)&Yr[k][64 + tj * 4];
#pragma unroll
      for (int i = 0; i < 8; ++i)
#pragma unroll
        for (int j = 0; j < 8; ++j) acc[i][j] += av[i] * bv[j];
    }
    __syncthreads();
  }
  float* pout = partial + (size_t)z * 65536;
#pragma unroll
  for (int i = 0; i < 8; ++i) {
    int row = i0 + ((i < 4) ? (ti * 4 + i) : (64 + ti * 4 + i - 4));
#pragma unroll
    for (int j = 0; j < 8; j += 4) {
      int col = j0 + ((j < 4) ? (tj * 4 + j) : (64 + tj * 4 + j - 4));
      *(float4*)(pout + (size_t)row * 256 + col) = *(float4*)&acc[i][j];
    }
  }
  if (diag && mc) {
    __syncthreads();
    Xs[hh][cc] = xP;
    __syncthreads();
    if (tid < 128) atomicAdd(&mc[i0 + tid], (Xs[0][tid] + Xs[1][tid]) * 16.0f); // *4^2
  }
}

__global__ void k_gram_reduce_sym(const float* __restrict__ partial, float* __restrict__ C) {
  int idx = blockIdx.x * 256 + threadIdx.x;
  int i = idx >> 8, j = idx & 255;
  int sidx = (i >= 128 && j < 128) ? (j * 256 + i) : idx;
  float s = 0.f;
  for (int z = 0; z < GRAM_KS; ++z) s += partial[(size_t)z * 65536 + sidx];
  C[idx] = s * 256.0f;    // *4^4
}

// ---------------- general Gram (fp16 in) + fused weighted colsums (scaled *4^6) ----------
__global__ __launch_bounds__(256) void k_gram(const __half* __restrict__ Xm,
    const __half* __restrict__ Ym, float* __restrict__ partial, int N,
    const float* __restrict__ wxA, const float* __restrict__ wxB, float* __restrict__ outX,
    const float* __restrict__ wyA, const float* __restrict__ wyB, float* __restrict__ outY) {
  __shared__ float Xs[16][132];
  __shared__ float Ys[16][132];
  __shared__ float wls[4][16];
  int tid = threadIdx.x;
  int i0 = blockIdx.x * 128, j0 = blockIdx.y * 128;
  int z = blockIdx.z;
  int chunk = (N + GRAM_KS - 1) / GRAM_KS;
  int rb = z * chunk, re = min(N, rb + chunk);
  int lk = tid >> 4;
  int tj = tid & 15;
  int lc = tj * 8;
  int ti = lk;
  bool doX = (outX != nullptr) && (blockIdx.y == 0);
  bool doY = (outY != nullptr) && (blockIdx.x == 0);
  int cc = tid & 127, hh = tid >> 7;
  float xA = 0, xB = 0, xP = 0, yA = 0, yB = 0, yP = 0;
  float acc[8][8] = {};
  for (int rr = rb; rr < re; rr += 16) {
    int r = rr + lk;
    float fx[8] = {}, fy[8] = {};
    if (r < re) {
      uint4 u = *(const uint4*)(Xm + (size_t)r * 256 + i0 + lc);
      uint4 v = *(const uint4*)(Ym + (size_t)r * 256 + j0 + lc);
      h8f(u, fx); h8f(v, fy);
    }
    *(float4*)&Xs[lk][lc] = *(float4*)&fx[0];
    *(float4*)&Xs[lk][lc + 4] = *(float4*)&fx[4];
    *(float4*)&Ys[lk][lc] = *(float4*)&fy[0];
    *(float4*)&Ys[lk][lc + 4] = *(float4*)&fy[4];
    if (tid < 64) {
      int grp = tid >> 4, kk = tid & 15, rw = rr + kk;
      const float* wp = (grp == 0) ? wxA : (grp == 1) ? wxB : (grp == 2) ? wyA : wyB;
      wls[grp][kk] = (wp && rw < re) ? wp[rw] : 0.f;
    }
    __syncthreads();
    if (doX) {
#pragma unroll
      for (int k = 0; k < 8; ++k) {
        float v = Xs[hh * 8 + k][cc];
        xP += v; xA += v * wls[0][hh * 8 + k]; xB += v * wls[1][hh * 8 + k];
      }
    }
    if (doY) {
#pragma unroll
      for (int k = 0; k < 8; ++k) {
        float v = Ys[hh * 8 + k][cc];
        yP += v; yA += v * wls[2][hh * 8 + k]; yB += v * wls[3][hh * 8 + k];
      }
    }
#pragma unroll
    for (int k = 0; k < 16; ++k) {
      float av[8], bv[8];
      *(float4*)&av[0] = *(const float4*)&Xs[k][ti * 4];
      *(float4*)&av[4] = *(const float4*)&Xs[k][64 + ti * 4];
      *(float4*)&bv[0] = *(const float4*)&Ys[k][tj * 4];
      *(float4*)&bv[4] = *(const float4*)&Ys[k][64 + tj * 4];
#pragma unroll
      for (int i = 0; i < 8; ++i)
#pragma unroll
        for (int j = 0; j < 8; ++j) acc[i][j] += av[i] * bv[j];
    }
    __syncthreads();
  }
  float* pout = partial + (size_t)z * 65536;
#pragma unroll
  for (int i = 0; i < 8; ++i) {
    int row = i0 + ((i < 4) ? (ti * 4 + i) : (64 + ti * 4 + i - 4));
#pragma unroll
    for (int j = 0; j < 8; j += 4) {
      int col = j0 + ((j < 4) ? (tj * 4 + j) : (64 + tj * 4 + j - 4));
      *(float4*)(pout + (size_t)row * 256 + col) = *(float4*)&acc[i][j];
    }
  }
  const float S6 = 4096.0f;   // 4^6
  if (doX) {
    __syncthreads();
    Xs[hh][cc] = xA;
    __syncthreads();
    if (tid < 128) atomicAdd(&outX[i0 + tid], (Xs[0][tid] + Xs[1][tid]) * S6);
    __syncthreads();
    Xs[hh][cc] = xB;
    __syncthreads();
    if (tid < 128) atomicAdd(&outX[256 + i0 + tid], (Xs[0][tid] + Xs[1][tid]) * S6);
    __syncthreads();
    Xs[hh][cc] = xP;
    __syncthreads();
    if (tid < 128) atomicAdd(&outX[512 + i0 + tid], (Xs[0][tid] + Xs[1][tid]) * S6);
  }
  if (doY) {
    __syncthreads();
    Ys[hh][cc] = yA;
    __syncthreads();
    if (tid < 128) atomicAdd(&outY[j0 + tid], (Ys[0][tid] + Ys[1][tid]) * S6);
    __syncthreads();
    Ys[hh][cc] = yB;
    __syncthreads();
    if (tid < 128) atomicAdd(&outY[256 + j0 + tid], (Ys[0][tid] + Ys[1][tid]) * S6);
    __syncthreads();
    Ys[hh][cc] = yP;
    __syncthreads();
    if (tid < 128) atomicAdd(&outY[512 + j0 + tid], (Ys[0][tid] + Ys[1][tid]) * S6);
  }
}

__global__ void k_gram_reduce(const float* __restrict__ partial, float* __restrict__ C) {
  int idx = blockIdx.x * 256 + threadIdx.x;
  float s = 0.f;
  for (int z = 0; z < GRAM_KS; ++z) s += partial[(size_t)z * 65536 + idx];
  C[idx] = s * 16777216.0f;   // *4^12
}

// ---------------- 8 scalar reductions over d/e vectors ----------------
__global__ __launch_bounds__(256) void k_dots(const float* __restrict__ d1,
    const float* __restrict__ e1, const float* __restrict__ d2,
    const float* __restrict__ e2, float* scal, int n) {
  int i = blockIdx.x * 256 + threadIdx.x;
  float a = 0, b = 0, c = 0, d = 0;
  if (i < n) { a = d1[i]; b = e1[i]; c = d2[i]; d = e2[i]; }
  float v[8] = { b * d, b * c, b, a * d, a * c, a, d, c };
#pragma unroll
  for (int j = 0; j < 8; ++j) {
    float x = v[j];
    for (int off = 32; off; off >>= 1) x += __shfl_down(x, off);
    v[j] = x;
  }
  if ((threadIdx.x & 63) == 0)
#pragma unroll
    for (int j = 0; j < 8; ++j) atomicAdd(&scal[j], v[j]);
}

// ---------------- t_j = w_j^T C w_j ; mv_j = w_j . m_raw ----------------
__global__ __launch_bounds__(256) void k_quad(const float* __restrict__ C,
    const float* __restrict__ W1, const float* __restrict__ m_raw,
    float* __restrict__ t, float* __restrict__ mv) {
  __shared__ float w[256];
  __shared__ float r1[256], r2[256];
  int j = blockIdx.x, tid = threadIdx.x;
  w[tid] = W1[j * 256 + tid];
  __syncthreads();
  float v = 0.f;
  for (int k = 0; k < 256; ++k) v += w[k] * C[k * 256 + tid];
  r1[tid] = v * w[tid];
  r2[tid] = w[tid] * m_raw[tid];
  __syncthreads();
  for (int off = 128; off; off >>= 1) {
    if (tid < off) { r1[tid] += r1[tid + off]; r2[tid] += r2[tid + off]; }
    __syncthreads();
  }
  if (tid == 0) { t[j] = r1[0]; mv[j] = r2[0]; }
}

// ---------------- BN coefficients (coalesced W2T/W3T) ----------------
__global__ __launch_bounds__(256) void k_bncoef(const float* __restrict__ t,
    const float* __restrict__ mv, const float* __restrict__ b1,
    const float* __restrict__ gamma, const float* __restrict__ beta,
    const float* __restrict__ W2T, const float* __restrict__ W3T,
    const float* __restrict__ b2, float* Dv, float* xv, float* yv, int n) {
  __shared__ float c[256], u[256];
  int j = threadIdx.x;
  float invn = 1.f / (float)n;
  float mean = mv[j] * invn + b1[j];
  float E2 = t[j] * invn + 2.f * b1[j] * mv[j] * invn + b1[j] * b1[j];
  float var = E2 - mean * mean;
  float D = gamma[j] * rsqrtf(var + 1e-5f);
  Dv[j] = D;
  c[j] = D * (b1[j] - mean) + beta[j];
  __syncthreads();
  float uu = 0.f;
  for (int k = 0; k < 256; ++k) uu += W2T[k * 256 + j] * c[k];
  u[j] = uu;
  __syncthreads();
  float xx = 0.f, yy = 0.f;
  for (int k = 0; k < 256; ++k) {
    xx += W3T[k * 256 + j] * u[k];
    yy += W3T[k * 256 + j] * b2[k];
  }
  xv[j] = xx;
  yv[j] = yy;
}

// ---------------- small 256x256 matmul (B coalesced) ----------------
__global__ __launch_bounds__(256) void k_mm_small(float* __restrict__ Cm,
    const float* __restrict__ A, const float* __restrict__ B,
    const float* __restrict__ s, int transA) {
  __shared__ float a[256];
  int i = blockIdx.x, j = threadIdx.x;
  float av = transA ? A[j * 256 + i] : A[i * 256 + j];
  a[j] = s ? av * s[j] : av;
  __syncthreads();
  float acc = 0.f;
  for (int k = 0; k < 256; ++k) acc += a[k] * B[k * 256 + j];
  Cm[i * 256 + j] = acc;
}

// ---------------- 6 matvecs ----------------
__global__ __launch_bounds__(256) void k_mv6(const float* __restrict__ R1,
    const float* __restrict__ R2, const float* __restrict__ pX,
    const float* __restrict__ qY, float* __restrict__ vout) {
  __shared__ float w[256];
  int b = blockIdx.x, j = threadIdx.x;
  const float* M = (b < 3) ? R1 : R2;
  const float* wv = (b < 3) ? (pX + b * 256) : (qY + (b - 3) * 256);
  w[j] = wv[j];
  __syncthreads();
  float s = 0.f;
  for (int k = 0; k < 256; ++k) s += M[k * 256 + j] * w[k];
  vout[b * 256 + j] = s;
}

// ---------------- final ----------------
__global__ __launch_bounds__(256) void k_mm_final(float* __restrict__ out,
    const float* __restrict__ R1, const float* __restrict__ T1,
    const float* __restrict__ vout,
    const float* __restrict__ x1, const float* __restrict__ x2,
    const float* __restrict__ yv, const float* __restrict__ b3,
    const float* __restrict__ scal, float fN) {
  __shared__ float a[256];
  int i = blockIdx.x, j = threadIdx.x;
  a[j] = R1[j * 256 + i];
  __syncthreads();
  float acc = 0.f;
  for (int k = 0; k < 256; ++k) acc += a[k] * T1[k * 256 + j];
  float s1 = scal[0] * x2[j] + scal[1] * yv[j] + scal[2] * b3[j];
  float s2 = scal[3] * x2[j] + scal[4] * yv[j] + scal[5] * b3[j];
  float s3 = scal[6] * x2[j] + scal[7] * yv[j] + fN * b3[j];
  acc += vout[i] * x2[j] + vout[256 + i] * yv[j] + vout[512 + i] * b3[j];
  acc += x1[i] * (vout[768 + j] + s1) + yv[i] * (vout[1024 + j] + s2)
       + b3[i] * (vout[1280 + j] + s3);
  out[i * 256 + j] = acc;
}

extern "C" void kernel_launch(void* const* d_in, const int* in_sizes, int n_in,
                              void* d_out, int out_size, void* d_ws, size_t ws_size,
                              hipStream_t stream) {
  const float* feature = (const float*)d_in[0];
  const int* src1 = (const int*)d_in[1];
  const int* dst1 = (const int*)d_in[2];
  const int* src2 = (const int*)d_in[3];
  const int* dst2 = (const int*)d_in[4];
  const float* W1 = (const float*)d_in[5];
  const float* b1 = (const float*)d_in[6];
  const float* W2 = (const float*)d_in[7];
  const float* b2 = (const float*)d_in[8];
  const float* W3 = (const float*)d_in[9];
  const float* b3 = (const float*)d_in[10];
  const float* gamma = (const float*)d_in[11];
  const float* beta = (const float*)d_in[12];
  const int N = in_sizes[0] / FDIM;
  const int E = in_sizes[1];
  float* out = (float*)d_out;

  // ---- workspace layout (fp16 tables + dedicated fp32 partial) ----
  size_t NF = (size_t)N * FDIM;
  __half* FH = (__half*)d_ws;
  __half* Xh = FH + NF;
  __half* Yh = Xh + NF;
  __half* G2A = Yh + NF;
  float* partial = (float*)(G2A + NF);
  int* rowptr1 = (int*)(partial + (size_t)GRAM_KS * 65536);
  int* rowptr2 = rowptr1 + (N + 1);
  int* cursor = rowptr2 + (N + 1);
  int* esrc1 = cursor + N;
  int* esrc2 = esrc1 + E;
  float* vtmp1 = (float*)(esrc2 + E);
  float* vtmp2 = vtmp1 + N;
  float* d1 = vtmp2 + N; float* e1 = d1 + N; float* d2 = e1 + N; float* e2 = d2 + N;
  float* C = e2 + N;
  float* mcA = C + 65536;            // zeroed span start
  float* mcB = mcA + 256;
  float* pX = mcB + 256;
  float* qY = pX + 768;
  float* scal = qY + 768;
  float* tq = scal + 16; float* mv = tq + 256;
  float* Dv = mv + 256; float* x1 = Dv + 256; float* x2 = x1 + 256; float* yv = x2 + 256;
  float* Q = yv + 256; float* R1 = Q + 65536; float* R2 = R1 + 65536;
  float* Z = R2 + 65536; float* T1 = Z + 65536;
  float* W2T = T1 + 65536; float* W3T = W2T + 65536;
  float* vout = W3T + 65536;
  int* blksum = (int*)(vout + 1536);
  int* blkoff = blksum + 1024;

  const int eb = (E + 255) / 256;
  const int nb = (N + 255) / 256;
  const int aggb = (N + 3) / 4;
  const int avb2 = (2 * N * 16 + 255) / 256;
  const int nblk = (N + 1023) / 1024;

  auto build = [&](const int* s_, const int* d_, int* rp, int* es) {
    hipMemsetAsync(cursor, 0, (size_t)N * sizeof(int), stream);
    k_hist<<<eb, 256, 0, stream>>>(d_, cursor, E);
    k_blksum<<<nblk, 256, 0, stream>>>(cursor, blksum, N);
    k_blkscan<<<1, 64, 0, stream>>>(blksum, blkoff, nblk);
    k_scan_blk<<<nblk, 256, 0, stream>>>(cursor, blkoff, rp, cursor, N);
    k_scatter<<<eb, 256, 0, stream>>>(s_, d_, cursor, es, E);
  };

  k_tr2<<<dim3(4, 4, 2), 256, 0, stream>>>(W2, W3, W2T, W3T);
  k_f2h<<<(int)((NF / 4 + 255) / 256), 256, 0, stream>>>(feature, FH, (int)(NF / 4));
  build(src1, dst1, rowptr1, esrc1);
  build(src2, dst2, rowptr2, esrc2);
  hipMemsetAsync(mcA, 0, (256 * 2 + 768 * 2 + 16) * sizeof(float), stream);

  // ---- d/e vectors (fp32, exact) ----
  k_aggv2<<<avb2, 256, 0, stream>>>(nullptr, nullptr, rowptr1, esrc1, rowptr2, esrc2,
                                    d1, d2, N, 1);
  k_aggv2<<<avb2, 256, 0, stream>>>(d1, d2, rowptr1, esrc1, rowptr2, esrc2,
                                    vtmp1, vtmp2, N, 0);
  k_aggv2<<<avb2, 256, 0, stream>>>(vtmp1, vtmp2, rowptr1, esrc1, rowptr2, esrc2,
                                    e1, e2, N, 0);
  k_dots<<<nb, 256, 0, stream>>>(d1, e1, d2, e2, scal, N);

  auto do_branch = [&](const int* rp, const int* es, __half* G2dst,
                       float* mc, float* xvec, float* Rdst) {
    k_aggh<<<aggb, 256, 0, stream>>>(FH, rp, es, Xh, N);
    k_aggh<<<aggb, 256, 0, stream>>>(Xh, rp, es, Yh, N);              // Yh = G0/16
    k_gram_sym<<<dim3(3, 1, GRAM_KS), 256, 0, stream>>>(Yh, partial, N, mc);
    k_gram_reduce_sym<<<256, 256, 0, stream>>>(partial, C);           // C true scale
    k_quad<<<256, 256, 0, stream>>>(C, W1, mc, tq, mv);
    k_bncoef<<<1, 256, 0, stream>>>(tq, mv, b1, gamma, beta, W2T, W3T, b2, Dv, xvec, yv, N);
    k_mm_small<<<256, 256, 0, stream>>>(Q, W1, W2T, Dv, 1);
    k_mm_small<<<256, 256, 0, stream>>>(Rdst, Q, W3T, nullptr, 0);
    k_aggh<<<aggb, 256, 0, stream>>>(Yh, rp, es, Xh, N);
    k_aggh<<<aggb, 256, 0, stream>>>(Xh, rp, es, Yh, N);              // A^4 F /256
    k_aggh<<<aggb, 256, 0, stream>>>(Yh, rp, es, Xh, N);
    k_aggh<<<aggb, 256, 0, stream>>>(Xh, rp, es, G2dst, N);           // G2/4096
  };

  do_branch(rowptr1, esrc1, G2A, mcA, x1, R1);
  do_branch(rowptr2, esrc2, Yh, mcB, x2, R2);   // branch-2 G2 lands in Yh

  // ---- final: Z = G2_1^T G2_2 (rescaled) + fused weighted colsums ----
  k_gram<<<dim3(2, 2, GRAM_KS), 256, 0, stream>>>(G2A, Yh, partial, N,
      e2, d2, pX, e1, d1, qY);
  k_gram_reduce<<<256, 256, 0, stream>>>(partial, Z);

  k_mm_small<<<256, 256, 0, stream>>>(T1, Z, R2, nullptr, 0);
  k_mv6<<<6, 256, 0, stream>>>(R1, R2, pX, qY, vout);
  k_mm_final<<<256, 256, 0, stream>>>(out, R1, T1, vout, x1, x2, yv, b3, scal, (float)N);
}